// Round 3
// baseline (18235.583 us; speedup 1.0000x reference)
//
#include <hip/hip_runtime.h>
#include <math.h>

// ---------------------------------------------------------------------------
// RNN_63153199120819  —  Round 3: fp16 MFMA rewrite.
//   * persistent LSTM kernel: 64 blocks x 16 batch rows, all 128 steps x 2
//     layers in ONE launch; h/c private to block (h via LDS, c in registers),
//     weights [Wih|Whh] streamed fp16 from L2 as MFMA B-fragments.
//   * MLP layers: fp16 16x16x32 MFMA GEMM (f32 accum, f32 bias, relu).
//   * u / hs share one fp16 [T,B,H] buffer (hs overwrites u in-place).
// Workspace ~86.5 MB.
// MFMA fragment layouts (measured, m89/m91): A[m=lane&15][k=(lane>>4)*8+j],
// B[n=lane&15][k=(lane>>4)*8+j] (B = W^T, W row-major [N][K]),
// D[row=(lane>>4)*4+reg][col=lane&15].
// ---------------------------------------------------------------------------

namespace {
constexpr int kT   = 128;
constexpr int kB   = 1024;
constexpr int kLag = 6;
constexpr int kH   = 256;
constexpr int kTc  = 16;          // MLP time chunk
constexpr int kMc  = kTc * kB;    // 16384 rows / chunk
}

typedef _Float16 half8 __attribute__((ext_vector_type(8)));
typedef float f32x4 __attribute__((ext_vector_type(4)));

__device__ __forceinline__ float sigm(float x) {
    return 1.f / (1.f + exp2f(-1.4426950408889634f * x));
}
__device__ __forceinline__ float tanh_(float x) {
    return 2.f / (1.f + exp2f(-2.8853900817779268f * x)) - 1.f;
}

// ---------------- prep kernels ---------------------------------------------
__global__ __launch_bounds__(256)
void cvt_f2h(const float* __restrict__ s, _Float16* __restrict__ d)
{
    const int i = blockIdx.x * 256 + threadIdx.x;
    d[i] = (_Float16)s[i];
}

// Wcat[g][0:256]=Wih[g][:], Wcat[g][256:512]=Whh[g][:]   (g = 0..1023)
__global__ __launch_bounds__(256)
void build_wcat(const float* __restrict__ Wih, const float* __restrict__ Whh,
                _Float16* __restrict__ d)
{
    const int i = blockIdx.x * 256 + threadIdx.x;   // over 1024*512
    const int row = i >> 9, col = i & 511;
    const float v = (col < 256) ? Wih[row * 256 + col] : Whh[row * 256 + col - 256];
    d[i] = (_Float16)v;
}

__global__ __launch_bounds__(256)
void add_bias(const float* __restrict__ a, const float* __restrict__ b,
              float* __restrict__ d)
{
    const int i = blockIdx.x * 256 + threadIdx.x;
    d[i] = a[i] + b[i];
}

// ---------------- first layer: u1 = relu(x @ Wi1^T + bi1), K=6, fp16 out ---
__global__ __launch_bounds__(256)
void in_mlp1(const float* __restrict__ x, const float* __restrict__ Wi1,
             const float* __restrict__ bi1, _Float16* __restrict__ out)
{
    const int idx = blockIdx.x * 256 + threadIdx.x;   // over Mc*H
    const int col = idx & (kH - 1);
    const int row = idx >> 8;
    const float* xr = x + (size_t)row * kLag;
    const float* w  = Wi1 + col * kLag;
    float s = bi1[col];
#pragma unroll
    for (int k = 0; k < kLag; ++k) s = fmaf(xr[k], w[k], s);
    out[idx] = (_Float16)fmaxf(s, 0.f);
}

// ---------------- fp16 MFMA GEMM: C[M,256] = relu(A[M,256] @ W[256,256]^T + b)
// grid (4, M/64), block 256 = 4 waves; wave w: rows [by*64+w*16, +16), cols [bx*64,+64)
__global__ __launch_bounds__(256)
void gemm_h16(const _Float16* __restrict__ A, const _Float16* __restrict__ W,
              const float* __restrict__ bias, _Float16* __restrict__ C)
{
    const int tid = threadIdx.x;
    const int w = tid >> 6, lane = tid & 63, q = lane >> 4, l15 = lane & 15;
    const int n0 = blockIdx.x * 64;
    const int r0 = blockIdx.y * 64 + w * 16;

    f32x4 acc[4];
#pragma unroll
    for (int nt = 0; nt < 4; ++nt) {
        const float bz = bias[n0 + nt * 16 + l15];
        acc[nt] = (f32x4){bz, bz, bz, bz};
    }
    const _Float16* arow = A + (size_t)(r0 + l15) * 256 + q * 8;
#pragma unroll
    for (int kk = 0; kk < 8; ++kk) {
        const half8 af = *(const half8*)(arow + kk * 32);
#pragma unroll
        for (int nt = 0; nt < 4; ++nt) {
            const half8 bf = *(const half8*)(W + (size_t)(n0 + nt * 16 + l15) * 256
                                             + kk * 32 + q * 8);
            acc[nt] = __builtin_amdgcn_mfma_f32_16x16x32_f16(af, bf, acc[nt], 0, 0, 0);
        }
    }
#pragma unroll
    for (int nt = 0; nt < 4; ++nt)
#pragma unroll
        for (int r = 0; r < 4; ++r) {
            const float v = fmaxf(acc[nt][r], 0.f);
            C[(size_t)(r0 + q * 4 + r) * 256 + n0 + nt * 16 + l15] = (_Float16)v;
        }
}

// ---------------- persistent 2-layer LSTM ----------------------------------
// 64 blocks x 256 threads (4 waves). Block owns batch rows [bid*16, +16).
// LDS Ain0/Ain1: [16][520] fp16; cols 0:256 = input (u_t / h0), 256:512 = own h.
// Wave w computes gate-cols {g*256 + w*64 + jt*16 + n} for g=0..3, jt=0..3.
// ubuf is read as u_t and overwritten with relu(h1_t) in place.
__global__ __launch_bounds__(256, 1)
void lstm_all(_Float16* __restrict__ ubuf,
              const _Float16* __restrict__ Wc0, const _Float16* __restrict__ Wc1,
              const float* __restrict__ bc0, const float* __restrict__ bc1)
{
    __shared__ _Float16 A0s[16 * 520];
    __shared__ _Float16 A1s[16 * 520];
    const int tid = threadIdx.x;
    const int w = tid >> 6, lane = tid & 63, q = lane >> 4, l15 = lane & 15;
    const int brow0 = blockIdx.x * 16;
    const int mld = tid >> 4, seg = tid & 15;   // cooperative-copy mapping

    // zero h regions (cols 256:512 of both buffers): 16 rows x 16 segs x 16 halves
    *(uint4*)&A0s[mld * 520 + 256 + seg * 16] = (uint4){0, 0, 0, 0};
    *(uint4*)&A0s[mld * 520 + 256 + seg * 16 + 8] = (uint4){0, 0, 0, 0};
    *(uint4*)&A1s[mld * 520 + 256 + seg * 16] = (uint4){0, 0, 0, 0};
    *(uint4*)&A1s[mld * 520 + 256 + seg * 16 + 8] = (uint4){0, 0, 0, 0};

    // preload biases: [g*4+jt] for this wave's column l15
    float b0v[16], b1v[16];
#pragma unroll
    for (int g = 0; g < 4; ++g)
#pragma unroll
        for (int jt = 0; jt < 4; ++jt) {
            const int n = g * 256 + w * 64 + jt * 16 + l15;
            b0v[g * 4 + jt] = bc0[n];
            b1v[g * 4 + jt] = bc1[n];
        }
    float c0s[16], c1s[16];
#pragma unroll
    for (int e = 0; e < 16; ++e) { c0s[e] = 0.f; c1s[e] = 0.f; }
    __syncthreads();

    for (int t = 0; t < kT; ++t) {
        // ---- S0: load u_t -> A0s[:, 0:256) ----
        {
            const uint4* src = (const uint4*)(ubuf
                + ((size_t)(t * kB + brow0 + mld)) * 256 + seg * 16);
            *(uint4*)&A0s[mld * 520 + seg * 16] = src[0];
            *(uint4*)&A0s[mld * 520 + seg * 16 + 8] = src[1];
        }
        __syncthreads();                                   // (a)

        _Float16 h0h[16], h1h[16];
        // ---- S1: layer 0 gates + cell ----
        {
            half8 af[16];
#pragma unroll
            for (int kk = 0; kk < 16; ++kk)
                af[kk] = *(const half8*)&A0s[l15 * 520 + kk * 32 + q * 8];
            f32x4 acc[16];
#pragma unroll
            for (int e = 0; e < 16; ++e)
                acc[e] = (f32x4){b0v[e], b0v[e], b0v[e], b0v[e]};
#pragma unroll
            for (int g = 0; g < 4; ++g)
#pragma unroll
                for (int jt = 0; jt < 4; ++jt) {
                    const _Float16* wrow = Wc0
                        + (size_t)(g * 256 + w * 64 + jt * 16 + l15) * 512 + q * 8;
#pragma unroll
                    for (int kk = 0; kk < 16; ++kk) {
                        const half8 bf = *(const half8*)(wrow + kk * 32);
                        acc[g * 4 + jt] = __builtin_amdgcn_mfma_f32_16x16x32_f16(
                            af[kk], bf, acc[g * 4 + jt], 0, 0, 0);
                    }
                }
#pragma unroll
            for (int jt = 0; jt < 4; ++jt)
#pragma unroll
                for (int r = 0; r < 4; ++r) {
                    const float gi = acc[0 * 4 + jt][r];
                    const float gf = acc[1 * 4 + jt][r];
                    const float gg = acc[2 * 4 + jt][r];
                    const float go = acc[3 * 4 + jt][r];
                    const float c2 = sigm(gf) * c0s[jt * 4 + r] + sigm(gi) * tanh_(gg);
                    c0s[jt * 4 + r] = c2;
                    h0h[jt * 4 + r] = (_Float16)(sigm(go) * tanh_(c2));
                }
        }
        __syncthreads();                                   // (b)
        // ---- S2: h0 -> A1s[:,0:256) (layer-1 input), A0s[:,256:) (next t) ----
#pragma unroll
        for (int jt = 0; jt < 4; ++jt)
#pragma unroll
            for (int r = 0; r < 4; ++r) {
                const int m = q * 4 + r;
                const int jc = w * 64 + jt * 16 + l15;
                A1s[m * 520 + jc] = h0h[jt * 4 + r];
                A0s[m * 520 + 256 + jc] = h0h[jt * 4 + r];
            }
        __syncthreads();                                   // (c)
        // ---- S3: layer 1 gates + cell ----
        {
            half8 af[16];
#pragma unroll
            for (int kk = 0; kk < 16; ++kk)
                af[kk] = *(const half8*)&A1s[l15 * 520 + kk * 32 + q * 8];
            f32x4 acc[16];
#pragma unroll
            for (int e = 0; e < 16; ++e)
                acc[e] = (f32x4){b1v[e], b1v[e], b1v[e], b1v[e]};
#pragma unroll
            for (int g = 0; g < 4; ++g)
#pragma unroll
                for (int jt = 0; jt < 4; ++jt) {
                    const _Float16* wrow = Wc1
                        + (size_t)(g * 256 + w * 64 + jt * 16 + l15) * 512 + q * 8;
#pragma unroll
                    for (int kk = 0; kk < 16; ++kk) {
                        const half8 bf = *(const half8*)(wrow + kk * 32);
                        acc[g * 4 + jt] = __builtin_amdgcn_mfma_f32_16x16x32_f16(
                            af[kk], bf, acc[g * 4 + jt], 0, 0, 0);
                    }
                }
#pragma unroll
            for (int jt = 0; jt < 4; ++jt)
#pragma unroll
                for (int r = 0; r < 4; ++r) {
                    const float gi = acc[0 * 4 + jt][r];
                    const float gf = acc[1 * 4 + jt][r];
                    const float gg = acc[2 * 4 + jt][r];
                    const float go = acc[3 * 4 + jt][r];
                    const float c2 = sigm(gf) * c1s[jt * 4 + r] + sigm(gi) * tanh_(gg);
                    c1s[jt * 4 + r] = c2;
                    h1h[jt * 4 + r] = (_Float16)(sigm(go) * tanh_(c2));
                }
        }
        __syncthreads();                                   // (d)
        // ---- S4: h1 -> A1s[:,256:) (next t) ----
#pragma unroll
        for (int jt = 0; jt < 4; ++jt)
#pragma unroll
            for (int r = 0; r < 4; ++r)
                A1s[(q * 4 + r) * 520 + 256 + w * 64 + jt * 16 + l15] = h1h[jt * 4 + r];
        __syncthreads();                                   // (e)
        // ---- S5: relu(h1) -> ubuf[t] (overwrite u_t) ----
        {
            half8 v0 = *(const half8*)&A1s[mld * 520 + 256 + seg * 16];
            half8 v1 = *(const half8*)&A1s[mld * 520 + 256 + seg * 16 + 8];
#pragma unroll
            for (int e = 0; e < 8; ++e) {
                v0[e] = (v0[e] > (_Float16)0.f) ? v0[e] : (_Float16)0.f;
                v1[e] = (v1[e] > (_Float16)0.f) ? v1[e] : (_Float16)0.f;
            }
            _Float16* dst = ubuf + ((size_t)(t * kB + brow0 + mld)) * 256 + seg * 16;
            *(half8*)dst = v0;
            *(half8*)(dst + 8) = v1;
        }
        // next S0 writes A0s[:,0:256) — no reader of that range is pending
    }
}

// ---------------- last layer: y = y2 @ Wo3^T + bo3, N=6, fp16 in -----------
__global__ __launch_bounds__(256)
void out_mlp3(const _Float16* __restrict__ y2, const float* __restrict__ Wo3,
              const float* __restrict__ bo3, float* __restrict__ out)
{
    const int lane = threadIdx.x & 63;
    const int row  = blockIdx.x * 4 + (threadIdx.x >> 6);
    const _Float16* yr = y2 + (size_t)row * kH + lane * 4;
    const float a0 = (float)yr[0], a1 = (float)yr[1], a2 = (float)yr[2], a3 = (float)yr[3];
    float s[kLag];
#pragma unroll
    for (int o = 0; o < kLag; ++o) {
        const float4 wv = *(const float4*)(Wo3 + o * kH + lane * 4);
        s[o] = a0 * wv.x + a1 * wv.y + a2 * wv.z + a3 * wv.w;
    }
#pragma unroll
    for (int off = 32; off > 0; off >>= 1) {
#pragma unroll
        for (int o = 0; o < kLag; ++o) s[o] += __shfl_down(s[o], off);
    }
    if (lane == 0) {
#pragma unroll
        for (int o = 0; o < kLag; ++o)
            out[(size_t)row * kLag + o] = s[o] + bo3[o];
    }
}

// ---------------------------------------------------------------------------
extern "C" void kernel_launch(void* const* d_in, const int* in_sizes, int n_in,
                              void* d_out, int out_size, void* d_ws, size_t ws_size,
                              hipStream_t stream)
{
    const float* x    = (const float*)d_in[0];
    const float* Wi1  = (const float*)d_in[1];
    const float* bi1  = (const float*)d_in[2];
    const float* Wi2  = (const float*)d_in[3];
    const float* bi2  = (const float*)d_in[4];
    const float* Wi3  = (const float*)d_in[5];
    const float* bi3  = (const float*)d_in[6];
    const float* Wih0 = (const float*)d_in[7];
    const float* Whh0 = (const float*)d_in[8];
    const float* bih0 = (const float*)d_in[9];
    const float* bhh0 = (const float*)d_in[10];
    const float* Wih1 = (const float*)d_in[11];
    const float* Whh1 = (const float*)d_in[12];
    const float* bih1 = (const float*)d_in[13];
    const float* bhh1 = (const float*)d_in[14];
    const float* Wo1  = (const float*)d_in[15];
    const float* bo1  = (const float*)d_in[16];
    const float* Wo2  = (const float*)d_in[17];
    const float* bo2  = (const float*)d_in[18];
    const float* Wo3  = (const float*)d_in[19];
    const float* bo3  = (const float*)d_in[20];
    float* outp = (float*)d_out;

    // ---- workspace layout ----
    char* p = (char*)d_ws;
    _Float16* ubuf = (_Float16*)p;  p += (size_t)kT * kB * kH * 2;   // 67.1 MB
    _Float16* s1   = (_Float16*)p;  p += (size_t)kMc * kH * 2;       // 8 MB
    _Float16* s2   = (_Float16*)p;  p += (size_t)kMc * kH * 2;       // 8 MB
    _Float16* Wc0  = (_Float16*)p;  p += (size_t)1024 * 512 * 2;     // 1 MB
    _Float16* Wc1  = (_Float16*)p;  p += (size_t)1024 * 512 * 2;     // 1 MB
    _Float16* W2h  = (_Float16*)p;  p += (size_t)kH * kH * 2;
    _Float16* W3h  = (_Float16*)p;  p += (size_t)kH * kH * 2;
    _Float16* Wo1h = (_Float16*)p;  p += (size_t)kH * kH * 2;
    _Float16* Wo2h = (_Float16*)p;  p += (size_t)kH * kH * 2;
    float* bc0 = (float*)p;  p += 1024 * 4;
    float* bc1 = (float*)p;  p += 1024 * 4;

    // ---- prep: fp16 weights, concatenated LSTM weights, combined biases ----
    cvt_f2h<<<kH * kH / 256, 256, 0, stream>>>(Wi2, W2h);
    cvt_f2h<<<kH * kH / 256, 256, 0, stream>>>(Wi3, W3h);
    cvt_f2h<<<kH * kH / 256, 256, 0, stream>>>(Wo1, Wo1h);
    cvt_f2h<<<kH * kH / 256, 256, 0, stream>>>(Wo2, Wo2h);
    build_wcat<<<1024 * 512 / 256, 256, 0, stream>>>(Wih0, Whh0, Wc0);
    build_wcat<<<1024 * 512 / 256, 256, 0, stream>>>(Wih1, Whh1, Wc1);
    add_bias<<<4, 256, 0, stream>>>(bih0, bhh0, bc0);
    add_bias<<<4, 256, 0, stream>>>(bih1, bhh1, bc1);

    // ---- input MLP (chunked): x -> s1 -> s2 -> ubuf ----
    for (int c = 0; c < kT / kTc; ++c) {
        in_mlp1<<<kMc * kH / 256, 256, 0, stream>>>(
            x + (size_t)c * kMc * kLag, Wi1, bi1, s1);
        gemm_h16<<<dim3(4, kMc / 64), 256, 0, stream>>>(s1, W2h, bi2, s2);
        gemm_h16<<<dim3(4, kMc / 64), 256, 0, stream>>>(
            s2, W3h, bi3, ubuf + (size_t)c * kMc * kH);
    }

    // ---- LSTM: one persistent launch; ubuf := relu(hs) in place ----
    lstm_all<<<kB / 16, 256, 0, stream>>>(ubuf, Wc0, Wc1, bc0, bc1);

    // ---- output MLP (chunked): ubuf -> s1 -> s2 -> out ----
    for (int c = 0; c < kT / kTc; ++c) {
        gemm_h16<<<dim3(4, kMc / 64), 256, 0, stream>>>(
            ubuf + (size_t)c * kMc * kH, Wo1h, bo1, s1);
        gemm_h16<<<dim3(4, kMc / 64), 256, 0, stream>>>(s1, Wo2h, bo2, s2);
        out_mlp3<<<kMc / 4, 256, 0, stream>>>(
            s2, Wo3, bo3, outp + (size_t)c * kMc * kLag);
    }
}

// Round 4
// 12525.879 us; speedup vs baseline: 1.4558x; 1.4558x over previous
//
#include <hip/hip_runtime.h>
#include <math.h>

// ---------------------------------------------------------------------------
// RNN_63153199120819 — Round 4: weight-stationary persistent LSTM.
// Grid 256 blocks = 16 batch-tiles (bi, 64 rows) x 16 h-slices (js, 16 cols).
// Each block: both layers' weight slice in LDS (133 KB), MFMA 64x64x512 gate
// tile per step-layer, cell for its slice, h via double-buffered global
// buffers, per-bi flag barrier (16 blocks) between phases. Cooperative launch
// guarantees co-residency. MLP layers unchanged from round 3 (fp16 MFMA).
// ---------------------------------------------------------------------------

namespace {
constexpr int kT   = 128;
constexpr int kB   = 1024;
constexpr int kLag = 6;
constexpr int kH   = 256;
constexpr int kTc  = 16;          // MLP time chunk
constexpr int kMc  = kTc * kB;    // 16384 rows / chunk
constexpr int kWS  = 520;         // LDS weight row stride (halves): 512 + 8
constexpr int kGS  = 66;          // LDS gate row stride (f32): 64 + 2
constexpr int kLdsBytes = 2 * 64 * kWS * 2 + 64 * kGS * 4;  // 133120+16896
}

typedef _Float16 half8 __attribute__((ext_vector_type(8)));
typedef _Float16 half2 __attribute__((ext_vector_type(2)));
typedef float f32x4 __attribute__((ext_vector_type(4)));

__device__ __forceinline__ float sigm(float x) {
    return 1.f / (1.f + exp2f(-1.4426950408889634f * x));
}
__device__ __forceinline__ float tanh_(float x) {
    return 2.f / (1.f + exp2f(-2.8853900817779268f * x)) - 1.f;
}

// ---------------- prep kernels ---------------------------------------------
__global__ __launch_bounds__(256)
void zero_fill(unsigned int* __restrict__ p)
{
    p[blockIdx.x * 256 + threadIdx.x] = 0u;
}

__global__ __launch_bounds__(256)
void cvt_f2h(const float* __restrict__ s, _Float16* __restrict__ d)
{
    const int i = blockIdx.x * 256 + threadIdx.x;
    d[i] = (_Float16)s[i];
}

// Wcat[g][0:256]=Wih[g][:], Wcat[g][256:512]=Whh[g][:]
__global__ __launch_bounds__(256)
void build_wcat(const float* __restrict__ Wih, const float* __restrict__ Whh,
                _Float16* __restrict__ d)
{
    const int i = blockIdx.x * 256 + threadIdx.x;   // over 1024*512
    const int row = i >> 9, col = i & 511;
    const float v = (col < 256) ? Wih[row * 256 + col] : Whh[row * 256 + col - 256];
    d[i] = (_Float16)v;
}

__global__ __launch_bounds__(256)
void add_bias(const float* __restrict__ a, const float* __restrict__ b,
              float* __restrict__ d)
{
    const int i = blockIdx.x * 256 + threadIdx.x;
    d[i] = a[i] + b[i];
}

// ---------------- first layer: u1 = relu(x @ Wi1^T + bi1), K=6, fp16 out ---
__global__ __launch_bounds__(256)
void in_mlp1(const float* __restrict__ x, const float* __restrict__ Wi1,
             const float* __restrict__ bi1, _Float16* __restrict__ out)
{
    const int idx = blockIdx.x * 256 + threadIdx.x;   // over Mc*H
    const int col = idx & (kH - 1);
    const int row = idx >> 8;
    const float* xr = x + (size_t)row * kLag;
    const float* w  = Wi1 + col * kLag;
    float s = bi1[col];
#pragma unroll
    for (int k = 0; k < kLag; ++k) s = fmaf(xr[k], w[k], s);
    out[idx] = (_Float16)fmaxf(s, 0.f);
}

// ---------------- fp16 MFMA GEMM: C[M,256] = relu(A[M,256] @ W[256,256]^T + b)
__global__ __launch_bounds__(256)
void gemm_h16(const _Float16* __restrict__ A, const _Float16* __restrict__ W,
              const float* __restrict__ bias, _Float16* __restrict__ C)
{
    const int tid = threadIdx.x;
    const int w = tid >> 6, lane = tid & 63, q = lane >> 4, l15 = lane & 15;
    const int n0 = blockIdx.x * 64;
    const int r0 = blockIdx.y * 64 + w * 16;

    f32x4 acc[4];
#pragma unroll
    for (int nt = 0; nt < 4; ++nt) {
        const float bz = bias[n0 + nt * 16 + l15];
        acc[nt] = (f32x4){bz, bz, bz, bz};
    }
    const _Float16* arow = A + (size_t)(r0 + l15) * 256 + q * 8;
#pragma unroll
    for (int kk = 0; kk < 8; ++kk) {
        const half8 af = *(const half8*)(arow + kk * 32);
#pragma unroll
        for (int nt = 0; nt < 4; ++nt) {
            const half8 bf = *(const half8*)(W + (size_t)(n0 + nt * 16 + l15) * 256
                                             + kk * 32 + q * 8);
            acc[nt] = __builtin_amdgcn_mfma_f32_16x16x32_f16(af, bf, acc[nt], 0, 0, 0);
        }
    }
#pragma unroll
    for (int nt = 0; nt < 4; ++nt)
#pragma unroll
        for (int r = 0; r < 4; ++r) {
            const float v = fmaxf(acc[nt][r], 0.f);
            C[(size_t)(r0 + q * 4 + r) * 256 + n0 + nt * 16 + l15] = (_Float16)v;
        }
}

// ---------------- persistent weight-stationary LSTM ------------------------
__device__ __forceinline__ void group_barrier(unsigned int* __restrict__ cptr,
                                              unsigned int target, int tid)
{
    __syncthreads();
    if (tid == 0) {
        __threadfence();
        __hip_atomic_fetch_add(cptr, 1u, __ATOMIC_RELEASE, __HIP_MEMORY_SCOPE_AGENT);
        while (__hip_atomic_load(cptr, __ATOMIC_ACQUIRE, __HIP_MEMORY_SCOPE_AGENT)
               < target)
            __builtin_amdgcn_s_sleep(4);
    }
    __syncthreads();
    __threadfence();
}

// one step-layer phase: gates 64x64x512 -> cell -> h writes
__device__ __forceinline__ void do_phase(
    int tid,
    const _Float16* __restrict__ alo,   // rows bi*64.., k 0..255 source
    const _Float16* __restrict__ ahi,   // rows bi*64.., k 256..511 source
    const _Float16* __restrict__ Wl,    // LDS weights: [64][kWS] (g*16+c rows)
    float* __restrict__ gl,             // LDS gate staging [64][kGS]
    const float* __restrict__ bsc,      // [e*4+g] per-thread biases
    float* __restrict__ cst,            // [2] per-thread c-state
    _Float16* __restrict__ hout,        // + (bi*64)*256 + js*16 pre-applied
    _Float16* __restrict__ uout)        // same, or nullptr
{
    const int w = tid >> 6, lane = tid & 63, q = lane >> 4, l15 = lane & 15;
    const int m0 = (w & 3) * 16;        // row tile within 64
    const int nb = (w >> 2) * 32;       // gate-col tile base (0 or 32)

    f32x4 acc0 = {0.f, 0.f, 0.f, 0.f}, acc1 = {0.f, 0.f, 0.f, 0.f};
    const _Float16* alor = alo + (size_t)(m0 + l15) * 256 + q * 8;
    const _Float16* ahir = ahi + (size_t)(m0 + l15) * 256 + q * 8;
    const _Float16* wr0 = Wl + (size_t)(nb + l15) * kWS + q * 8;
    const _Float16* wr1 = Wl + (size_t)(nb + 16 + l15) * kWS + q * 8;
#pragma unroll
    for (int kk = 0; kk < 16; ++kk) {
        const half8 af = (kk < 8) ? *(const half8*)(alor + kk * 32)
                                  : *(const half8*)(ahir + (kk - 8) * 32);
        const half8 bf0 = *(const half8*)(wr0 + kk * 32);
        const half8 bf1 = *(const half8*)(wr1 + kk * 32);
        acc0 = __builtin_amdgcn_mfma_f32_16x16x32_f16(af, bf0, acc0, 0, 0, 0);
        acc1 = __builtin_amdgcn_mfma_f32_16x16x32_f16(af, bf1, acc1, 0, 0, 0);
    }
#pragma unroll
    for (int r = 0; r < 4; ++r) {
        gl[(m0 + q * 4 + r) * kGS + nb + l15]      = acc0[r];
        gl[(m0 + q * 4 + r) * kGS + nb + 16 + l15] = acc1[r];
    }
    __syncthreads();

    // cell: thread -> (row = tid>>3, cols cc, cc+1); gate n = g*16 + c
    const int crow = tid >> 3, cc = (tid & 7) * 2;
    const float* gr = gl + crow * kGS;
    _Float16 hp[2];
#pragma unroll
    for (int e = 0; e < 2; ++e) {
        const float gi = gr[0 * 16 + cc + e] + bsc[e * 4 + 0];
        const float gf = gr[1 * 16 + cc + e] + bsc[e * 4 + 1];
        const float gg = gr[2 * 16 + cc + e] + bsc[e * 4 + 2];
        const float go = gr[3 * 16 + cc + e] + bsc[e * 4 + 3];
        const float c2 = sigm(gf) * cst[e] + sigm(gi) * tanh_(gg);
        cst[e] = c2;
        hp[e] = (_Float16)(sigm(go) * tanh_(c2));
    }
    *(half2*)(hout + (size_t)crow * 256 + cc) = (half2){hp[0], hp[1]};
    if (uout) {
        const _Float16 z = (_Float16)0.f;
        *(half2*)(uout + (size_t)crow * 256 + cc) =
            (half2){hp[0] > z ? hp[0] : z, hp[1] > z ? hp[1] : z};
    }
}

__global__ __launch_bounds__(512, 1)
void lstm_all(_Float16* __restrict__ ubuf,
              const _Float16* __restrict__ Wc0, const _Float16* __restrict__ Wc1,
              const float* __restrict__ bc0, const float* __restrict__ bc1,
              _Float16* __restrict__ h0b, _Float16* __restrict__ h1b,
              unsigned int* __restrict__ cnt)
{
    extern __shared__ char lds[];
    _Float16* Wl = (_Float16*)lds;                         // [2][64][kWS]
    float* gl = (float*)(lds + 2 * 64 * kWS * 2);          // [64][kGS]

    const int tid = threadIdx.x;
    const int bi = blockIdx.x & 15;     // batch tile (same-XCD heuristic)
    const int js = blockIdx.x >> 4;     // h-col slice

    // ---- load weight slices to LDS (once): row r=g*16+c <- global g*256+js*16+c
    for (int i = tid; i < 2 * 64 * 64; i += 512) {         // half8 units
        const int l = i >> 12;
        const int r = (i >> 6) & 63;
        const int ks = i & 63;
        const int g = r >> 4, c = r & 15;
        const _Float16* src = (l ? Wc1 : Wc0) + (size_t)(g * 256 + js * 16 + c) * 512
                              + ks * 8;
        *(half8*)&Wl[(size_t)l * 64 * kWS + (size_t)r * kWS + ks * 8] =
            *(const half8*)src;
    }

    // ---- per-thread biases (cell mapping: row tid>>3, cols cc, cc+1) ----
    const int cc = (tid & 7) * 2;
    float bs0[8], bs1[8];
#pragma unroll
    for (int e = 0; e < 2; ++e)
#pragma unroll
        for (int g = 0; g < 4; ++g) {
            bs0[e * 4 + g] = bc0[g * 256 + js * 16 + cc + e];
            bs1[e * 4 + g] = bc1[g * 256 + js * 16 + cc + e];
        }
    float cst0[2] = {0.f, 0.f}, cst1[2] = {0.f, 0.f};
    unsigned int* cptr = cnt + bi * 32;   // 128-B spaced counters
    __syncthreads();

    for (int t = 0; t < kT; ++t) {
        const int rp = t & 1, wp = rp ^ 1;
        // ---- layer 0: A = [u_t || h0_prev] ----
        do_phase(tid,
                 ubuf + ((size_t)t * kB + bi * 64) * 256,
                 h0b + ((size_t)rp * kB + bi * 64) * 256,
                 Wl, gl, bs0, cst0,
                 h0b + ((size_t)wp * kB + bi * 64) * 256 + js * 16,
                 nullptr);
        group_barrier(cptr, (unsigned)(16 * (2 * t + 1)), tid);
        // ---- layer 1: A = [h0_cur || h1_prev]; relu(h1) -> ubuf[t] ----
        do_phase(tid,
                 h0b + ((size_t)wp * kB + bi * 64) * 256,
                 h1b + ((size_t)rp * kB + bi * 64) * 256,
                 Wl + 64 * kWS, gl, bs1, cst1,
                 h1b + ((size_t)wp * kB + bi * 64) * 256 + js * 16,
                 ubuf + ((size_t)t * kB + bi * 64) * 256 + js * 16);
        if (t < kT - 1)
            group_barrier(cptr, (unsigned)(16 * (2 * t + 2)), tid);
    }
}

// ---------------- last layer: y = y2 @ Wo3^T + bo3, N=6, fp16 in -----------
__global__ __launch_bounds__(256)
void out_mlp3(const _Float16* __restrict__ y2, const float* __restrict__ Wo3,
              const float* __restrict__ bo3, float* __restrict__ out)
{
    const int lane = threadIdx.x & 63;
    const int row  = blockIdx.x * 4 + (threadIdx.x >> 6);
    const _Float16* yr = y2 + (size_t)row * kH + lane * 4;
    const float a0 = (float)yr[0], a1 = (float)yr[1], a2 = (float)yr[2], a3 = (float)yr[3];
    float s[kLag];
#pragma unroll
    for (int o = 0; o < kLag; ++o) {
        const float4 wv = *(const float4*)(Wo3 + o * kH + lane * 4);
        s[o] = a0 * wv.x + a1 * wv.y + a2 * wv.z + a3 * wv.w;
    }
#pragma unroll
    for (int off = 32; off > 0; off >>= 1) {
#pragma unroll
        for (int o = 0; o < kLag; ++o) s[o] += __shfl_down(s[o], off);
    }
    if (lane == 0) {
#pragma unroll
        for (int o = 0; o < kLag; ++o)
            out[(size_t)row * kLag + o] = s[o] + bo3[o];
    }
}

// ---------------------------------------------------------------------------
extern "C" void kernel_launch(void* const* d_in, const int* in_sizes, int n_in,
                              void* d_out, int out_size, void* d_ws, size_t ws_size,
                              hipStream_t stream)
{
    const float* x    = (const float*)d_in[0];
    const float* Wi1  = (const float*)d_in[1];
    const float* bi1  = (const float*)d_in[2];
    const float* Wi2  = (const float*)d_in[3];
    const float* bi2  = (const float*)d_in[4];
    const float* Wi3  = (const float*)d_in[5];
    const float* bi3  = (const float*)d_in[6];
    const float* Wih0 = (const float*)d_in[7];
    const float* Whh0 = (const float*)d_in[8];
    const float* bih0 = (const float*)d_in[9];
    const float* bhh0 = (const float*)d_in[10];
    const float* Wih1 = (const float*)d_in[11];
    const float* Whh1 = (const float*)d_in[12];
    const float* bih1 = (const float*)d_in[13];
    const float* bhh1 = (const float*)d_in[14];
    const float* Wo1  = (const float*)d_in[15];
    const float* bo1  = (const float*)d_in[16];
    const float* Wo2  = (const float*)d_in[17];
    const float* bo2  = (const float*)d_in[18];
    const float* Wo3  = (const float*)d_in[19];
    const float* bo3  = (const float*)d_in[20];
    float* outp = (float*)d_out;

    // ---- workspace layout ----
    char* p = (char*)d_ws;
    _Float16* ubuf = (_Float16*)p;  p += (size_t)kT * kB * kH * 2;   // 67.1 MB
    _Float16* s1   = (_Float16*)p;  p += (size_t)kMc * kH * 2;       // 8 MB
    _Float16* s2   = (_Float16*)p;  p += (size_t)kMc * kH * 2;       // 8 MB
    _Float16* Wc0  = (_Float16*)p;  p += (size_t)1024 * 512 * 2;     // 1 MB
    _Float16* Wc1  = (_Float16*)p;  p += (size_t)1024 * 512 * 2;     // 1 MB
    _Float16* W2h  = (_Float16*)p;  p += (size_t)kH * kH * 2;
    _Float16* W3h  = (_Float16*)p;  p += (size_t)kH * kH * 2;
    _Float16* Wo1h = (_Float16*)p;  p += (size_t)kH * kH * 2;
    _Float16* Wo2h = (_Float16*)p;  p += (size_t)kH * kH * 2;
    float* bc0 = (float*)p;  p += 1024 * 4;
    float* bc1 = (float*)p;  p += 1024 * 4;
    // h double-buffers + counters (contiguous, zeroed together)
    _Float16* h0b = (_Float16*)p;  p += (size_t)2 * kB * kH * 2;     // 1 MB
    _Float16* h1b = (_Float16*)p;  p += (size_t)2 * kB * kH * 2;     // 1 MB
    unsigned int* cnt = (unsigned int*)p;  p += 2048;                // 16 x 128B

    // ---- prep ----
    // zero h0b,h1b,cnt: (2*1048576 + 2048) bytes = 524800 u32 = 2050 blocks
    zero_fill<<<2050, 256, 0, stream>>>((unsigned int*)h0b);
    cvt_f2h<<<kH * kH / 256, 256, 0, stream>>>(Wi2, W2h);
    cvt_f2h<<<kH * kH / 256, 256, 0, stream>>>(Wi3, W3h);
    cvt_f2h<<<kH * kH / 256, 256, 0, stream>>>(Wo1, Wo1h);
    cvt_f2h<<<kH * kH / 256, 256, 0, stream>>>(Wo2, Wo2h);
    build_wcat<<<1024 * 512 / 256, 256, 0, stream>>>(Wih0, Whh0, Wc0);
    build_wcat<<<1024 * 512 / 256, 256, 0, stream>>>(Wih1, Whh1, Wc1);
    add_bias<<<4, 256, 0, stream>>>(bih0, bhh0, bc0);
    add_bias<<<4, 256, 0, stream>>>(bih1, bhh1, bc1);

    // ---- input MLP (chunked): x -> s1 -> s2 -> ubuf ----
    for (int c = 0; c < kT / kTc; ++c) {
        in_mlp1<<<kMc * kH / 256, 256, 0, stream>>>(
            x + (size_t)c * kMc * kLag, Wi1, bi1, s1);
        gemm_h16<<<dim3(4, kMc / 64), 256, 0, stream>>>(s1, W2h, bi2, s2);
        gemm_h16<<<dim3(4, kMc / 64), 256, 0, stream>>>(
            s2, W3h, bi3, ubuf + (size_t)c * kMc * kH);
    }

    // ---- LSTM: cooperative weight-stationary persistent kernel ----
    static bool attr_set = false;
    if (!attr_set) {
        hipFuncSetAttribute((const void*)lstm_all,
                            hipFuncAttributeMaxDynamicSharedMemorySize, kLdsBytes);
        attr_set = true;
    }
    void* args[] = {&ubuf, &Wc0, &Wc1, &bc0, &bc1, &h0b, &h1b, &cnt};
    hipLaunchCooperativeKernel((const void*)lstm_all, dim3(256), dim3(512),
                               args, kLdsBytes, stream);

    // ---- output MLP (chunked): ubuf -> s1 -> s2 -> out ----
    for (int c = 0; c < kT / kTc; ++c) {
        gemm_h16<<<dim3(4, kMc / 64), 256, 0, stream>>>(
            ubuf + (size_t)c * kMc * kH, Wo1h, bo1, s1);
        gemm_h16<<<dim3(4, kMc / 64), 256, 0, stream>>>(s1, Wo2h, bo2, s2);
        out_mlp3<<<kMc / 4, 256, 0, stream>>>(
            s2, Wo3, bo3, outp + (size_t)c * kMc * kLag);
    }
}

// Round 5
// 3212.392 us; speedup vs baseline: 5.6766x; 3.8992x over previous
//
#include <hip/hip_runtime.h>
#include <math.h>

// ---------------------------------------------------------------------------
// RNN_63153199120819 — Round 5: weight-stationary persistent LSTM with
// XCD-local barrier groups and NO cache-wide fences.
// Grid 256 blocks (cooperative, 150KB LDS => exactly 1 block/CU => exactly 32
// blocks/XCD). Each block reads HW_REG_XCC_ID, takes a rank within its XCD,
// and becomes (bi = xcd*2 + rank/16, js = rank%16). The 16 blocks of a bi
// group share one XCD, so h exchange goes through that XCD's L2:
//   writes = plain stores (write-through L2), reads = relaxed agent atomic
//   loads (sc0, L1 bypass), barrier = relaxed agent atomic RMW (coherent).
// MLP layers unchanged (fp16 MFMA, validated rounds 3-4).
// ---------------------------------------------------------------------------

namespace {
constexpr int kT   = 128;
constexpr int kB   = 1024;
constexpr int kLag = 6;
constexpr int kH   = 256;
constexpr int kTc  = 16;          // MLP time chunk
constexpr int kMc  = kTc * kB;    // 16384 rows / chunk
constexpr int kWS  = 520;         // LDS weight row stride (halves)
constexpr int kGS  = 66;          // LDS gate row stride (f32)
constexpr int kLdsBytes = 2 * 64 * kWS * 2 + 64 * kGS * 4;  // 150016 B
}

typedef _Float16 half8 __attribute__((ext_vector_type(8)));
typedef _Float16 half2 __attribute__((ext_vector_type(2)));
typedef float f32x4 __attribute__((ext_vector_type(4)));

__device__ __forceinline__ float sigm(float x) {
    return 1.f / (1.f + exp2f(-1.4426950408889634f * x));
}
__device__ __forceinline__ float tanh_(float x) {
    return 2.f / (1.f + exp2f(-2.8853900817779268f * x)) - 1.f;
}

// coherent (L1-bypass, L2-hit) 16-byte load as two 64-bit agent atomics
__device__ __forceinline__ half8 ld_h8_coh(const _Float16* p) {
    const unsigned long long* q = (const unsigned long long*)p;
    union { unsigned long long u[2]; half8 h; } r;
    r.u[0] = __hip_atomic_load(q + 0, __ATOMIC_RELAXED, __HIP_MEMORY_SCOPE_AGENT);
    r.u[1] = __hip_atomic_load(q + 1, __ATOMIC_RELAXED, __HIP_MEMORY_SCOPE_AGENT);
    return r.h;
}

// ---------------- prep kernels ---------------------------------------------
__global__ __launch_bounds__(256)
void zero_fill(unsigned int* __restrict__ p)
{
    p[blockIdx.x * 256 + threadIdx.x] = 0u;
}

__global__ __launch_bounds__(256)
void cvt_f2h(const float* __restrict__ s, _Float16* __restrict__ d)
{
    const int i = blockIdx.x * 256 + threadIdx.x;
    d[i] = (_Float16)s[i];
}

// Wcat[g][0:256]=Wih[g][:], Wcat[g][256:512]=Whh[g][:]
__global__ __launch_bounds__(256)
void build_wcat(const float* __restrict__ Wih, const float* __restrict__ Whh,
                _Float16* __restrict__ d)
{
    const int i = blockIdx.x * 256 + threadIdx.x;   // over 1024*512
    const int row = i >> 9, col = i & 511;
    const float v = (col < 256) ? Wih[row * 256 + col] : Whh[row * 256 + col - 256];
    d[i] = (_Float16)v;
}

__global__ __launch_bounds__(256)
void add_bias(const float* __restrict__ a, const float* __restrict__ b,
              float* __restrict__ d)
{
    const int i = blockIdx.x * 256 + threadIdx.x;
    d[i] = a[i] + b[i];
}

// ---------------- first layer: u1 = relu(x @ Wi1^T + bi1), K=6, fp16 out ---
__global__ __launch_bounds__(256)
void in_mlp1(const float* __restrict__ x, const float* __restrict__ Wi1,
             const float* __restrict__ bi1, _Float16* __restrict__ out)
{
    const int idx = blockIdx.x * 256 + threadIdx.x;   // over Mc*H
    const int col = idx & (kH - 1);
    const int row = idx >> 8;
    const float* xr = x + (size_t)row * kLag;
    const float* w  = Wi1 + col * kLag;
    float s = bi1[col];
#pragma unroll
    for (int k = 0; k < kLag; ++k) s = fmaf(xr[k], w[k], s);
    out[idx] = (_Float16)fmaxf(s, 0.f);
}

// ---------------- fp16 MFMA GEMM: C[M,256] = relu(A[M,256] @ W[256,256]^T + b)
__global__ __launch_bounds__(256)
void gemm_h16(const _Float16* __restrict__ A, const _Float16* __restrict__ W,
              const float* __restrict__ bias, _Float16* __restrict__ C)
{
    const int tid = threadIdx.x;
    const int w = tid >> 6, lane = tid & 63, q = lane >> 4, l15 = lane & 15;
    const int n0 = blockIdx.x * 64;
    const int r0 = blockIdx.y * 64 + w * 16;

    f32x4 acc[4];
#pragma unroll
    for (int nt = 0; nt < 4; ++nt) {
        const float bz = bias[n0 + nt * 16 + l15];
        acc[nt] = (f32x4){bz, bz, bz, bz};
    }
    const _Float16* arow = A + (size_t)(r0 + l15) * 256 + q * 8;
#pragma unroll
    for (int kk = 0; kk < 8; ++kk) {
        const half8 af = *(const half8*)(arow + kk * 32);
#pragma unroll
        for (int nt = 0; nt < 4; ++nt) {
            const half8 bf = *(const half8*)(W + (size_t)(n0 + nt * 16 + l15) * 256
                                             + kk * 32 + q * 8);
            acc[nt] = __builtin_amdgcn_mfma_f32_16x16x32_f16(af, bf, acc[nt], 0, 0, 0);
        }
    }
#pragma unroll
    for (int nt = 0; nt < 4; ++nt)
#pragma unroll
        for (int r = 0; r < 4; ++r) {
            const float v = fmaxf(acc[nt][r], 0.f);
            C[(size_t)(r0 + q * 4 + r) * 256 + n0 + nt * 16 + l15] = (_Float16)v;
        }
}

// ---------------- persistent weight-stationary LSTM ------------------------
// XCD-local barrier: plain-store drain via __syncthreads (waves drain vmcnt
// before s_barrier), relaxed agent RMW on counter (always coherent).
__device__ __forceinline__ void xbar(unsigned int* __restrict__ cptr,
                                     unsigned int target, int tid)
{
    __syncthreads();
    if (tid == 0) {
        __hip_atomic_fetch_add(cptr, 1u, __ATOMIC_RELAXED,
                               __HIP_MEMORY_SCOPE_AGENT);
        while (__hip_atomic_fetch_add(cptr, 0u, __ATOMIC_RELAXED,
                                      __HIP_MEMORY_SCOPE_AGENT) < target)
            __builtin_amdgcn_s_sleep(2);
    }
    __syncthreads();
}

// one step-layer phase: gates 64x64x512 -> cell -> h writes
// CLO: alo needs coherent loads (it is an h buffer); ahi always coherent.
template<bool CLO>
__device__ __forceinline__ void do_phase(
    int tid,
    const _Float16* __restrict__ alo,   // rows bi*64.., k 0..255 source
    const _Float16* __restrict__ ahi,   // rows bi*64.., k 256..511 source (h)
    const _Float16* __restrict__ Wl,    // LDS weights [64][kWS]
    float* __restrict__ gl,             // LDS gate staging [64][kGS]
    const float* __restrict__ bsc,      // per-thread biases [e*4+g]
    float* __restrict__ cst,            // per-thread c-state [2]
    _Float16* __restrict__ hout,        // + (bi*64)*256 + js*16 pre-applied
    _Float16* __restrict__ uout)        // same, or nullptr
{
    const int w = tid >> 6, lane = tid & 63, q = lane >> 4, l15 = lane & 15;
    const int m0 = (w & 3) * 16;        // row tile within 64
    const int nb = (w >> 2) * 32;       // gate-col tile base (0 or 32)

    f32x4 acc0 = {0.f, 0.f, 0.f, 0.f}, acc1 = {0.f, 0.f, 0.f, 0.f};
    const _Float16* alor = alo + (size_t)(m0 + l15) * 256 + q * 8;
    const _Float16* ahir = ahi + (size_t)(m0 + l15) * 256 + q * 8;
    const _Float16* wr0 = Wl + (size_t)(nb + l15) * kWS + q * 8;
    const _Float16* wr1 = Wl + (size_t)(nb + 16 + l15) * kWS + q * 8;
#pragma unroll
    for (int kk = 0; kk < 16; ++kk) {
        half8 af;
        if (kk < 8) af = CLO ? ld_h8_coh(alor + kk * 32)
                             : *(const half8*)(alor + kk * 32);
        else        af = ld_h8_coh(ahir + (kk - 8) * 32);
        const half8 bf0 = *(const half8*)(wr0 + kk * 32);
        const half8 bf1 = *(const half8*)(wr1 + kk * 32);
        acc0 = __builtin_amdgcn_mfma_f32_16x16x32_f16(af, bf0, acc0, 0, 0, 0);
        acc1 = __builtin_amdgcn_mfma_f32_16x16x32_f16(af, bf1, acc1, 0, 0, 0);
    }
#pragma unroll
    for (int r = 0; r < 4; ++r) {
        gl[(m0 + q * 4 + r) * kGS + nb + l15]      = acc0[r];
        gl[(m0 + q * 4 + r) * kGS + nb + 16 + l15] = acc1[r];
    }
    __syncthreads();

    // cell: thread -> (row = tid>>3, cols cc, cc+1); gate n = g*16 + c
    const int crow = tid >> 3, cc = (tid & 7) * 2;
    const float* gr = gl + crow * kGS;
    _Float16 hp[2];
#pragma unroll
    for (int e = 0; e < 2; ++e) {
        const float gi = gr[0 * 16 + cc + e] + bsc[e * 4 + 0];
        const float gf = gr[1 * 16 + cc + e] + bsc[e * 4 + 1];
        const float gg = gr[2 * 16 + cc + e] + bsc[e * 4 + 2];
        const float go = gr[3 * 16 + cc + e] + bsc[e * 4 + 3];
        const float c2 = sigm(gf) * cst[e] + sigm(gi) * tanh_(gg);
        cst[e] = c2;
        hp[e] = (_Float16)(sigm(go) * tanh_(c2));
    }
    *(half2*)(hout + (size_t)crow * 256 + cc) = (half2){hp[0], hp[1]};
    if (uout) {
        const _Float16 z = (_Float16)0.f;
        *(half2*)(uout + (size_t)crow * 256 + cc) =
            (half2){hp[0] > z ? hp[0] : z, hp[1] > z ? hp[1] : z};
    }
}

__global__ __launch_bounds__(512, 1)
void lstm_all(_Float16* __restrict__ ubuf,
              const _Float16* __restrict__ Wc0, const _Float16* __restrict__ Wc1,
              const float* __restrict__ bc0, const float* __restrict__ bc1,
              _Float16* __restrict__ h0b, _Float16* __restrict__ h1b,
              unsigned int* __restrict__ cnt)
{
    extern __shared__ char lds[];
    _Float16* Wl = (_Float16*)lds;                         // [2][64][kWS]
    float* gl = (float*)(lds + 2 * 64 * kWS * 2);          // [64][kGS]

    const int tid = threadIdx.x;

    // ---- XCD discovery -> role (bi, js); groups are provably intra-XCD ----
    // 150KB LDS => 1 block/CU; cooperative => co-resident => 32 blocks/XCD.
    __shared__ int sh_bi, sh_js;
    if (tid == 0) {
        // HW_REG_XCC_ID = 20, offset 0, width 32
        unsigned int xcd = __builtin_amdgcn_s_getreg(20 | (31 << 11)) & 7u;
        unsigned int rank = __hip_atomic_fetch_add(cnt + 512 + xcd * 16, 1u,
            __ATOMIC_RELAXED, __HIP_MEMORY_SCOPE_AGENT);
        sh_bi = (int)(xcd * 2 + (rank >> 4));
        sh_js = (int)(rank & 15);
    }
    __syncthreads();
    const int bi = sh_bi, js = sh_js;
    unsigned int* cptr = cnt + bi * 32;   // group counter, 128B spaced

    // ---- load weight slices to LDS (once) ----
    for (int i = tid; i < 2 * 64 * 64; i += 512) {         // half8 units
        const int l = i >> 12;
        const int r = (i >> 6) & 63;
        const int ks = i & 63;
        const int g = r >> 4, c = r & 15;
        const _Float16* src = (l ? Wc1 : Wc0)
            + (size_t)(g * 256 + js * 16 + c) * 512 + ks * 8;
        *(half8*)&Wl[(size_t)l * 64 * kWS + (size_t)r * kWS + ks * 8] =
            *(const half8*)src;
    }

    // ---- per-thread biases (cell mapping: row tid>>3, cols cc, cc+1) ----
    const int cc = (tid & 7) * 2;
    float bs0[8], bs1[8];
#pragma unroll
    for (int e = 0; e < 2; ++e)
#pragma unroll
        for (int g = 0; g < 4; ++g) {
            bs0[e * 4 + g] = bc0[g * 256 + js * 16 + cc + e];
            bs1[e * 4 + g] = bc1[g * 256 + js * 16 + cc + e];
        }
    float cst0[2] = {0.f, 0.f}, cst1[2] = {0.f, 0.f};
    __syncthreads();

    for (int t = 0; t < kT; ++t) {
        const int rp = t & 1, wp = rp ^ 1;
        // ---- layer 0: A = [u_t || h0_prev] ----
        do_phase<false>(tid,
                 ubuf + ((size_t)t * kB + bi * 64) * 256,
                 h0b + ((size_t)rp * kB + bi * 64) * 256,
                 Wl, gl, bs0, cst0,
                 h0b + ((size_t)wp * kB + bi * 64) * 256 + js * 16,
                 nullptr);
        xbar(cptr, (unsigned)(16 * (2 * t + 1)), tid);
        // ---- layer 1: A = [h0_cur || h1_prev]; relu(h1) -> ubuf[t] ----
        do_phase<true>(tid,
                 h0b + ((size_t)wp * kB + bi * 64) * 256,
                 h1b + ((size_t)rp * kB + bi * 64) * 256,
                 Wl + 64 * kWS, gl, bs1, cst1,
                 h1b + ((size_t)wp * kB + bi * 64) * 256 + js * 16,
                 ubuf + ((size_t)t * kB + bi * 64) * 256 + js * 16);
        if (t < kT - 1)
            xbar(cptr, (unsigned)(16 * (2 * t + 2)), tid);
    }
}

// ---------------- last layer: y = y2 @ Wo3^T + bo3, N=6, fp16 in -----------
__global__ __launch_bounds__(256)
void out_mlp3(const _Float16* __restrict__ y2, const float* __restrict__ Wo3,
              const float* __restrict__ bo3, float* __restrict__ out)
{
    const int lane = threadIdx.x & 63;
    const int row  = blockIdx.x * 4 + (threadIdx.x >> 6);
    const _Float16* yr = y2 + (size_t)row * kH + lane * 4;
    const float a0 = (float)yr[0], a1 = (float)yr[1], a2 = (float)yr[2], a3 = (float)yr[3];
    float s[kLag];
#pragma unroll
    for (int o = 0; o < kLag; ++o) {
        const float4 wv = *(const float4*)(Wo3 + o * kH + lane * 4);
        s[o] = a0 * wv.x + a1 * wv.y + a2 * wv.z + a3 * wv.w;
    }
#pragma unroll
    for (int off = 32; off > 0; off >>= 1) {
#pragma unroll
        for (int o = 0; o < kLag; ++o) s[o] += __shfl_down(s[o], off);
    }
    if (lane == 0) {
#pragma unroll
        for (int o = 0; o < kLag; ++o)
            out[(size_t)row * kLag + o] = s[o] + bo3[o];
    }
}

// ---------------------------------------------------------------------------
extern "C" void kernel_launch(void* const* d_in, const int* in_sizes, int n_in,
                              void* d_out, int out_size, void* d_ws, size_t ws_size,
                              hipStream_t stream)
{
    const float* x    = (const float*)d_in[0];
    const float* Wi1  = (const float*)d_in[1];
    const float* bi1  = (const float*)d_in[2];
    const float* Wi2  = (const float*)d_in[3];
    const float* bi2  = (const float*)d_in[4];
    const float* Wi3  = (const float*)d_in[5];
    const float* bi3  = (const float*)d_in[6];
    const float* Wih0 = (const float*)d_in[7];
    const float* Whh0 = (const float*)d_in[8];
    const float* bih0 = (const float*)d_in[9];
    const float* bhh0 = (const float*)d_in[10];
    const float* Wih1 = (const float*)d_in[11];
    const float* Whh1 = (const float*)d_in[12];
    const float* bih1 = (const float*)d_in[13];
    const float* bhh1 = (const float*)d_in[14];
    const float* Wo1  = (const float*)d_in[15];
    const float* bo1  = (const float*)d_in[16];
    const float* Wo2  = (const float*)d_in[17];
    const float* bo2  = (const float*)d_in[18];
    const float* Wo3  = (const float*)d_in[19];
    const float* bo3  = (const float*)d_in[20];
    float* outp = (float*)d_out;

    // ---- workspace layout ----
    char* p = (char*)d_ws;
    _Float16* ubuf = (_Float16*)p;  p += (size_t)kT * kB * kH * 2;   // 67.1 MB
    _Float16* s1   = (_Float16*)p;  p += (size_t)kMc * kH * 2;       // 8 MB
    _Float16* s2   = (_Float16*)p;  p += (size_t)kMc * kH * 2;       // 8 MB
    _Float16* Wc0  = (_Float16*)p;  p += (size_t)1024 * 512 * 2;     // 1 MB
    _Float16* Wc1  = (_Float16*)p;  p += (size_t)1024 * 512 * 2;     // 1 MB
    _Float16* W2h  = (_Float16*)p;  p += (size_t)kH * kH * 2;
    _Float16* W3h  = (_Float16*)p;  p += (size_t)kH * kH * 2;
    _Float16* Wo1h = (_Float16*)p;  p += (size_t)kH * kH * 2;
    _Float16* Wo2h = (_Float16*)p;  p += (size_t)kH * kH * 2;
    float* bc0 = (float*)p;  p += 1024 * 4;
    float* bc1 = (float*)p;  p += 1024 * 4;
    // zeroed region: h double-buffers + counters (contiguous)
    _Float16* h0b = (_Float16*)p;  p += (size_t)2 * kB * kH * 2;     // 1 MB
    _Float16* h1b = (_Float16*)p;  p += (size_t)2 * kB * kH * 2;     // 1 MB
    unsigned int* cnt = (unsigned int*)p;  p += 4096;  // 16 group + 8 xcd ctrs

    // ---- prep ----
    // zero h0b,h1b,cnt: (2*1048576 + 4096)/4 = 525312 u32 = 2052 blocks
    zero_fill<<<2052, 256, 0, stream>>>((unsigned int*)h0b);
    cvt_f2h<<<kH * kH / 256, 256, 0, stream>>>(Wi2, W2h);
    cvt_f2h<<<kH * kH / 256, 256, 0, stream>>>(Wi3, W3h);
    cvt_f2h<<<kH * kH / 256, 256, 0, stream>>>(Wo1, Wo1h);
    cvt_f2h<<<kH * kH / 256, 256, 0, stream>>>(Wo2, Wo2h);
    build_wcat<<<1024 * 512 / 256, 256, 0, stream>>>(Wih0, Whh0, Wc0);
    build_wcat<<<1024 * 512 / 256, 256, 0, stream>>>(Wih1, Whh1, Wc1);
    add_bias<<<4, 256, 0, stream>>>(bih0, bhh0, bc0);
    add_bias<<<4, 256, 0, stream>>>(bih1, bhh1, bc1);

    // ---- input MLP (chunked): x -> s1 -> s2 -> ubuf ----
    for (int c = 0; c < kT / kTc; ++c) {
        in_mlp1<<<kMc * kH / 256, 256, 0, stream>>>(
            x + (size_t)c * kMc * kLag, Wi1, bi1, s1);
        gemm_h16<<<dim3(4, kMc / 64), 256, 0, stream>>>(s1, W2h, bi2, s2);
        gemm_h16<<<dim3(4, kMc / 64), 256, 0, stream>>>(
            s2, W3h, bi3, ubuf + (size_t)c * kMc * kH);
    }

    // ---- LSTM: cooperative weight-stationary persistent kernel ----
    static bool attr_set = false;
    if (!attr_set) {
        hipFuncSetAttribute((const void*)lstm_all,
                            hipFuncAttributeMaxDynamicSharedMemorySize, kLdsBytes);
        attr_set = true;
    }
    void* args[] = {&ubuf, &Wc0, &Wc1, &bc0, &bc1, &h0b, &h1b, &cnt};
    hipLaunchCooperativeKernel((const void*)lstm_all, dim3(256), dim3(512),
                               args, kLdsBytes, stream);

    // ---- output MLP (chunked): ubuf -> s1 -> s2 -> out ----
    for (int c = 0; c < kT / kTc; ++c) {
        gemm_h16<<<dim3(4, kMc / 64), 256, 0, stream>>>(
            ubuf + (size_t)c * kMc * kH, Wo1h, bo1, s1);
        gemm_h16<<<dim3(4, kMc / 64), 256, 0, stream>>>(s1, Wo2h, bo2, s2);
        out_mlp3<<<kMc / 4, 256, 0, stream>>>(
            s2, Wo3, bo3, outp + (size_t)c * kMc * kLag);
    }
}